// Round 1
// baseline (562.059 us; speedup 1.0000x reference)
//
#include <hip/hip_runtime.h>
#include <math.h>

typedef __attribute__((ext_vector_type(8))) short bf16x8;
typedef __attribute__((ext_vector_type(4))) float f32x4;

#define NWMASK 192
#define SCALE_Q 0.17677669529663687f

__device__ __forceinline__ unsigned short f2bf(float f) {
  union { float f; unsigned u; } v; v.f = f;
  return (unsigned short)((v.u + 0x7fffu + ((v.u >> 16) & 1u)) >> 16);
}

__device__ __forceinline__ unsigned pkbf(float a, float b) {
#if defined(__has_builtin)
#if __has_builtin(__builtin_amdgcn_cvt_pk_bf16_f32)
  auto r = __builtin_amdgcn_cvt_pk_bf16_f32(a, b);
  union { decltype(r) v; unsigned u; } c; c.v = r; return c.u;
#else
  return (unsigned)f2bf(a) | ((unsigned)f2bf(b) << 16);
#endif
#else
  return (unsigned)f2bf(a) | ((unsigned)f2bf(b) << 16);
#endif
}

__device__ __forceinline__ void pack8s(unsigned short* dst, const float* src) {
  float4 lo = *(const float4*)(src);
  float4 hi = *(const float4*)(src + 4);
  uint4 pk;
  pk.x = pkbf(lo.x, lo.y); pk.y = pkbf(lo.z, lo.w);
  pk.z = pkbf(hi.x, hi.y); pk.w = pkbf(hi.z, hi.w);
  *(uint4*)dst = pk;
}

// ---- prep: blocks 0-47 wpack, 48-63 pbT (+lam on blk48), 64-255 maskT ----
__global__ void prep_kernel(const float* __restrict__ Wqkv, const float* __restrict__ Wqkv2,
                            const float* __restrict__ Wproj,
                            const float* __restrict__ Wp1, const float* __restrict__ bp1,
                            const float* __restrict__ Wp2, const float* __restrict__ bp2,
                            const float* __restrict__ mask,
                            const float* __restrict__ lq1, const float* __restrict__ lk1,
                            const float* __restrict__ lq2, const float* __restrict__ lk2,
                            unsigned short* __restrict__ Wb, float* __restrict__ pbT,
                            float* __restrict__ maskT, float* __restrict__ lamOut) {
  int bid = blockIdx.x;
  if (bid < 48) {
    int gid = bid * 256 + threadIdx.x;            // 12288 fragment groups
    int l15 = gid & 15, quad = (gid >> 4) & 3, ks = (gid >> 6) & 3, ft = gid >> 8;
    int row = ft * 16 + l15;
    const float* src = (row < 384) ? (Wqkv + (size_t)row * 128)
                     : (row < 640) ? (Wqkv2 + (size_t)(row - 384) * 128)
                                   : (Wproj + (size_t)(row - 640) * 128);
    pack8s(Wb + (size_t)gid * 8, src + ks * 32 + quad * 8);
  } else if (bid < 64) {
    int idx = (bid - 48) * 256 + threadIdx.x;     // (i,j), 4096 total
    int i = idx >> 6, j = idx & 63;
    float dx = (float)((i & 7) - (j & 7));
    float dy = -(float)((i >> 3) - (j >> 3));
    float r = sqrtf(dx*dx + dy*dy + 1e-9f);
    float theta = atan2f(dx, dy);
    float p0 = r * (1.0f / 9.899494936611665f);
    float p1 = (theta + 3.14159265358979323846f) * (1.0f / 6.283185307179586f);
    float a0 = 0.f, a1 = 0.f, a2 = 0.f, a3 = 0.f;
    for (int f = 0; f < 64; ++f) {
      float hpre = p0 * Wp1[2*f] + p1 * Wp1[2*f+1] + bp1[f];
      float g = 0.5f * hpre * (1.0f + erff(hpre * 0.70710678118654752f));
      a0 += Wp2[f]       * g;
      a1 += Wp2[64 + f]  * g;
      a2 += Wp2[128 + f] * g;
      a3 += Wp2[192 + f] * g;
    }
    int o = j * 64 + i;                           // transposed
    pbT[o]          = a0 + bp2[0];
    pbT[4096 + o]   = a1 + bp2[1];
    pbT[8192 + o]   = a2 + bp2[2];
    pbT[12288 + o]  = a3 + bp2[3];
    if (bid == 48 && threadIdx.x == 0) {
      float s1 = 0.f, s2 = 0.f;
      for (int k = 0; k < 16; ++k) { s1 += lq1[k]*lk1[k]; s2 += lq2[k]*lk2[k]; }
      lamOut[0] = expf(s1) - expf(s2) + 0.2f;
    }
  } else {
    // per-window LDS transpose, coalesced both sides
    __shared__ float tile[64][65];
    int wm = bid - 64;
    const float* src = mask + (size_t)wm * 4096;
#pragma unroll
    for (int u = 0; u < 4; ++u) {
      int o = u * 1024 + threadIdx.x * 4;
      float4 v = *(const float4*)(src + o);
      int r = o >> 6, c = o & 63;
      tile[r][c] = v.x; tile[r][c+1] = v.y; tile[r][c+2] = v.z; tile[r][c+3] = v.w;
    }
    __syncthreads();
    float* dst = maskT + (size_t)wm * 4096;
#pragma unroll
    for (int u = 0; u < 4; ++u) {
      int o = u * 1024 + threadIdx.x * 4;
      int c = o >> 6, r = o & 63;
      float4 v;
      v.x = tile[r][c]; v.y = tile[r+1][c]; v.z = tile[r+2][c]; v.w = tile[r+3][c];
      *(float4*)(dst + o) = v;
    }
  }
}

// ---- fully fused: one block = one window, wave w = head w ----
// LDS pool 32 KB (u16 smem[16384]):
//   wave slice w: [w*4096, w*4096+2048) QBUF -> P-half;  [+2048, +4096) KBUF -> VT
//   after B3:     [0, 8192) OBUF bf16 [64][128]
// x is NOT staged: MFMA A-fragments are loaded from global per use (L1/L2-resident).
// P is stored in two 32-k halves (QBUF slot reused), PV consumes each half in turn.
// softmax: plain E=exp(s), no max-sub, no normalization (row-sum cancels in RMSNorm).
__global__ __launch_bounds__(256, 4)
void fused_win(const float* __restrict__ x, const unsigned short* __restrict__ Wb,
               const float* __restrict__ bqkv, const float* __restrict__ bqkv2,
               const float* __restrict__ lamBuf,
               const float* __restrict__ subln, const float* __restrict__ bproj,
               const float* __restrict__ pbT, const float* __restrict__ maskT,
               float* __restrict__ out) {
  __shared__ unsigned short smem[16384];

  const int b = blockIdx.x;
  const int t = threadIdx.x;
  const int w = t >> 6;            // wave == head
  const int lane = t & 63;
  const int l15 = lane & 15;
  const int quad = lane >> 4;
  const int h = w;
  const f32x4 zero4 = (f32x4){0.f, 0.f, 0.f, 0.f};
  const float lam = lamBuf[0];
  const float* xg = x + (size_t)b * 8192;

  unsigned short* PW = smem + w * 4096;

  // x A-fragment straight from global (f32 -> bf16 pack)
  auto ldXG = [&](int mi, int ks) -> bf16x8 {
    const float* p = xg + (size_t)(mi * 16 + l15) * 128 + ks * 32 + quad * 8;
    float4 lo = *(const float4*)p;
    float4 hi = *(const float4*)(p + 4);
    uint4 pk;
    pk.x = pkbf(lo.x, lo.y); pk.y = pkbf(lo.z, lo.w);
    pk.z = pkbf(hi.x, hi.y); pk.w = pkbf(hi.z, hi.w);
    union { uint4 u; bf16x8 v; } cv; cv.u = pk; return cv.v;
  };
  auto ldWbF = [&](int ft, int ks) -> bf16x8 {
    return *(const bf16x8*)(Wb + ((((size_t)ft * 4 + ks) * 4 + quad) * 16 + l15) * 8);
  };

  auto proj4 = [&](int ft0, int ft1, int ft2, int ft3, f32x4 (&acc)[4][4]) {
#pragma unroll
    for (int mi = 0; mi < 4; ++mi)
#pragma unroll
      for (int nj = 0; nj < 4; ++nj) acc[mi][nj] = zero4;
#pragma unroll
    for (int ks = 0; ks < 4; ++ks) {
      bf16x8 xa[4], wf[4];
#pragma unroll
      for (int mi = 0; mi < 4; ++mi) xa[mi] = ldXG(mi, ks);
      wf[0] = ldWbF(ft0, ks); wf[1] = ldWbF(ft1, ks);
      wf[2] = ldWbF(ft2, ks); wf[3] = ldWbF(ft3, ks);
      __builtin_amdgcn_s_setprio(1);
#pragma unroll
      for (int mi = 0; mi < 4; ++mi)
#pragma unroll
        for (int nj = 0; nj < 4; ++nj)
          acc[mi][nj] = __builtin_amdgcn_mfma_f32_16x16x32_bf16(xa[mi], wf[nj], acc[mi][nj], 0, 0, 0);
      __builtin_amdgcn_s_setprio(0);
    }
  };
  // 2-tile projection (keeps live acc small while S is resident)
  auto proj2 = [&](int ft0, int ft1, f32x4 (&acc)[4][4]) {
#pragma unroll
    for (int mi = 0; mi < 4; ++mi) { acc[mi][0] = zero4; acc[mi][1] = zero4; }
#pragma unroll
    for (int ks = 0; ks < 4; ++ks) {
      bf16x8 w0 = ldWbF(ft0, ks), w1 = ldWbF(ft1, ks);
#pragma unroll
      for (int mi = 0; mi < 4; ++mi) {
        bf16x8 xa = ldXG(mi, ks);
        __builtin_amdgcn_s_setprio(1);
        acc[mi][0] = __builtin_amdgcn_mfma_f32_16x16x32_bf16(xa, w0, acc[mi][0], 0, 0, 0);
        acc[mi][1] = __builtin_amdgcn_mfma_f32_16x16x32_bf16(xa, w1, acc[mi][1], 0, 0, 0);
        __builtin_amdgcn_s_setprio(0);
      }
    }
  };
  // store one 64x32 matrix (columns njo,njo+1 of acc) into a [64][32] swizzled buf
  auto storeM = [&](f32x4 (&acc)[4][4], int njo, const float* bias, float sc,
                    unsigned short* buf) {
#pragma unroll
    for (int nj = 0; nj < 2; ++nj) {
      int c32 = nj * 16 + l15;
      float bv = bias[c32];
#pragma unroll
      for (int mi = 0; mi < 4; ++mi) {
        f32x4 a = acc[mi][njo + nj];
        unsigned p01 = pkbf((a[0] + bv) * sc, (a[1] + bv) * sc);
        unsigned p23 = pkbf((a[2] + bv) * sc, (a[3] + bv) * sc);
        int r0 = mi * 16 + quad * 4;
        buf[(r0+0) * 32 + (((c32 >> 3) ^ ((r0+0) & 3)) * 8) + (c32 & 7)] = (unsigned short)p01;
        buf[(r0+1) * 32 + (((c32 >> 3) ^ ((r0+1) & 3)) * 8) + (c32 & 7)] = (unsigned short)(p01 >> 16);
        buf[(r0+2) * 32 + (((c32 >> 3) ^ ((r0+2) & 3)) * 8) + (c32 & 7)] = (unsigned short)p23;
        buf[(r0+3) * 32 + (((c32 >> 3) ^ ((r0+3) & 3)) * 8) + (c32 & 7)] = (unsigned short)(p23 >> 16);
      }
    }
  };
  // S (in/out) += QBUF x KBUF^T, optionally seeding C from pbT+maskT
  auto qkTiles = [&](f32x4 (&S)[4][4], bool seedBias) {
    bf16x8 qa[4], kb[4];
#pragma unroll
    for (int mi = 0; mi < 4; ++mi) {
      int row = mi * 16 + l15;
      qa[mi] = *(const bf16x8*)(&PW[row * 32 + ((quad ^ (l15 & 3)) * 8)]);
      kb[mi] = *(const bf16x8*)(&PW[2048 + row * 32 + ((quad ^ (l15 & 3)) * 8)]);
    }
    const float* pbh = pbT + h * 4096;
    const float* mkh = maskT + (size_t)(b % NWMASK) * 4096;
    __builtin_amdgcn_s_setprio(1);
#pragma unroll
    for (int mi = 0; mi < 4; ++mi)
#pragma unroll
      for (int ni = 0; ni < 4; ++ni) {
        f32x4 c;
        if (seedBias) {
          int off = (ni * 16 + l15) * 64 + mi * 16 + quad * 4;
          float4 p4 = *(const float4*)(pbh + off);
          float4 m4 = *(const float4*)(mkh + off);
          c[0] = p4.x + m4.x; c[1] = p4.y + m4.y;
          c[2] = p4.z + m4.z; c[3] = p4.w + m4.w;
        } else c = S[mi][ni];
        S[mi][ni] = __builtin_amdgcn_mfma_f32_16x16x32_bf16(qa[mi], kb[ni], c, 0, 0, 0);
      }
    __builtin_amdgcn_s_setprio(0);
  };
  // store one packed E half (k columns 0..31 local) into PW[0,2048)
  auto storeHalf = [&](unsigned (&pe)[4][4]) {
#pragma unroll
    for (int mi = 0; mi < 4; ++mi)
#pragma unroll
      for (int reg = 0; reg < 4; ++reg) {
        int row = mi * 16 + quad * 4 + reg;
        unsigned short* prow = PW + row * 32;
        unsigned v = pe[mi][reg];
        int sw = row & 3;
        prow[(((l15 >> 3) + 0) ^ sw) * 8 + (l15 & 7)] = (unsigned short)v;
        prow[(((l15 >> 3) + 2) ^ sw) * 8 + (l15 & 7)] = (unsigned short)(v >> 16);
      }
  };

  // ===== secondary: q2' = (q2+b)*(-lam*scale), k2 -> S = q2'k2 + pb + mask =====
  f32x4 S[4][4];
  {
    f32x4 acc[4][4];
    proj4(24 + 2*h, 25 + 2*h, 32 + 2*h, 33 + 2*h, acc);
    storeM(acc, 0, bqkv2 + h*32, -lam * SCALE_Q, PW);
    storeM(acc, 2, bqkv2 + 128 + h*32, 1.0f, PW + 2048);
    qkTiles(S, true);
  }
  // ===== primary: q,k (split proj2 to cap regs while S is live) =====
  {
    f32x4 acc[4][4];
    proj2(2*h, 1 + 2*h, acc);
    storeM(acc, 0, bqkv + h*32, SCALE_Q, PW);
    proj2(8 + 2*h, 9 + 2*h, acc);
    storeM(acc, 0, bqkv + 128 + h*32, 1.0f, PW + 2048);
    qkTiles(S, false);
  }

  // ===== E = exp(S), packed to bf16 pairs; S dies here =====
  unsigned pe01[4][4], pe23[4][4];
#pragma unroll
  for (int mi = 0; mi < 4; ++mi)
#pragma unroll
    for (int reg = 0; reg < 4; ++reg) {
      float e0 = __expf(S[mi][0][reg]);
      float e1 = __expf(S[mi][1][reg]);
      float e2 = __expf(S[mi][2][reg]);
      float e3 = __expf(S[mi][3][reg]);
      pe01[mi][reg] = pkbf(e0, e1);
      pe23[mi][reg] = pkbf(e2, e3);
    }
  storeHalf(pe01);                        // P k-cols 0..31 -> QBUF slot

  // ===== v projection + VT [32 d][64 tok] into KBUF slot =====
  {
    f32x4 av[4][4];
    proj2(16 + 2*h, 17 + 2*h, av);
    unsigned short* VT = PW + 2048;
#pragma unroll
    for (int nd = 0; nd < 2; ++nd) {
      int d = nd * 16 + l15;
      float bias = bqkv[256 + h * 32 + d];
#pragma unroll
      for (int mi = 0; mi < 4; ++mi) {
        int tok0 = mi * 16 + quad * 4;
        uint2 pk;
        pk.x = pkbf(av[mi][nd][0] + bias, av[mi][nd][1] + bias);
        pk.y = pkbf(av[mi][nd][2] + bias, av[mi][nd][3] + bias);
        *(uint2*)(&VT[d * 64 + (((tok0 >> 3) ^ (d & 7)) * 8) + (tok0 & 7)]) = pk;
      }
    }
  }

  // ===== PV in two k-halves -> O (unnormalized); RMSNorm folds the sum away =====
  float ov0[4][4], ov1[4][4];
  {
    unsigned short* VT = PW + 2048;
    f32x4 O[4][2];
#pragma unroll
    for (int mi = 0; mi < 4; ++mi) { O[mi][0] = zero4; O[mi][1] = zero4; }
    // kc = 0 (P half 0 already in LDS)
    {
      bf16x8 pa[4], vb[2];
#pragma unroll
      for (int mi = 0; mi < 4; ++mi) {
        int row = mi * 16 + l15;
        pa[mi] = *(const bf16x8*)(&PW[row * 32 + ((quad ^ (l15 & 3)) * 8)]);
      }
#pragma unroll
      for (int nd = 0; nd < 2; ++nd) {
        int d = nd * 16 + l15;
        vb[nd] = *(const bf16x8*)(&VT[d * 64 + ((quad ^ (d & 7)) * 8)]);
      }
      __builtin_amdgcn_s_setprio(1);
#pragma unroll
      for (int mi = 0; mi < 4; ++mi) {
        O[mi][0] = __builtin_amdgcn_mfma_f32_16x16x32_bf16(pa[mi], vb[0], O[mi][0], 0, 0, 0);
        O[mi][1] = __builtin_amdgcn_mfma_f32_16x16x32_bf16(pa[mi], vb[1], O[mi][1], 0, 0, 0);
      }
      __builtin_amdgcn_s_setprio(0);
    }
    storeHalf(pe23);                      // overwrite with P k-cols 32..63
    // kc = 1
    {
      bf16x8 pa[4], vb[2];
#pragma unroll
      for (int mi = 0; mi < 4; ++mi) {
        int row = mi * 16 + l15;
        pa[mi] = *(const bf16x8*)(&PW[row * 32 + ((quad ^ (l15 & 3)) * 8)]);
      }
#pragma unroll
      for (int nd = 0; nd < 2; ++nd) {
        int d = nd * 16 + l15;
        vb[nd] = *(const bf16x8*)(&VT[d * 64 + (((4 + quad) ^ (d & 7)) * 8)]);
      }
      __builtin_amdgcn_s_setprio(1);
#pragma unroll
      for (int mi = 0; mi < 4; ++mi) {
        O[mi][0] = __builtin_amdgcn_mfma_f32_16x16x32_bf16(pa[mi], vb[0], O[mi][0], 0, 0, 0);
        O[mi][1] = __builtin_amdgcn_mfma_f32_16x16x32_bf16(pa[mi], vb[1], O[mi][1], 0, 0, 0);
      }
      __builtin_amdgcn_s_setprio(0);
    }
    float sw0 = subln[l15] * 0.8f;
    float sw1 = subln[16 + l15] * 0.8f;
#pragma unroll
    for (int mi = 0; mi < 4; ++mi)
#pragma unroll
      for (int reg = 0; reg < 4; ++reg) {
        float a0 = O[mi][0][reg], a1 = O[mi][1][reg];
        float ss = a0 * a0 + a1 * a1;
        ss += __shfl_xor(ss, 1);
        ss += __shfl_xor(ss, 2);
        ss += __shfl_xor(ss, 4);
        ss += __shfl_xor(ss, 8);
        float rs = 1.0f / sqrtf(ss * (1.0f / 32.0f));   // eps*sum^2 negligible
        ov0[mi][reg] = a0 * rs * sw0;
        ov1[mi][reg] = a1 * rs * sw1;
      }
  }

  __syncthreads();                                   // B3: all PV/VT reads done

  // ===== O -> OBUF [64][128] bf16 at smem[0,8192) =====
  {
    int c0 = h * 32 + l15, c1 = h * 32 + 16 + l15;
#pragma unroll
    for (int mi = 0; mi < 4; ++mi)
#pragma unroll
      for (int reg = 0; reg < 4; ++reg) {
        int row = mi * 16 + quad * 4 + reg;
        unsigned short* orow = smem + row * 128;
        unsigned p = pkbf(ov0[mi][reg], ov1[mi][reg]);
        orow[(((c0 >> 3) ^ (row & 7)) * 8) + (c0 & 7)] = (unsigned short)p;
        orow[(((c1 >> 3) ^ (row & 7)) * 8) + (c1 & 7)] = (unsigned short)(p >> 16);
      }
  }
  __syncthreads();                                   // B4

  // ===== out-projection =====
  {
    f32x4 po[4][2];
#pragma unroll
    for (int mi = 0; mi < 4; ++mi) { po[mi][0] = zero4; po[mi][1] = zero4; }
#pragma unroll
    for (int ks = 0; ks < 4; ++ks) {
      bf16x8 oa[4];
#pragma unroll
      for (int mi = 0; mi < 4; ++mi) {
        int row = mi * 16 + l15;
        oa[mi] = *(const bf16x8*)(&smem[row * 128 + (((ks * 4 + quad) ^ (l15 & 7)) * 8)]);
      }
      bf16x8 w0 = ldWbF(40 + 2*w, ks), w1 = ldWbF(41 + 2*w, ks);
      __builtin_amdgcn_s_setprio(1);
#pragma unroll
      for (int mi = 0; mi < 4; ++mi) {
        po[mi][0] = __builtin_amdgcn_mfma_f32_16x16x32_bf16(oa[mi], w0, po[mi][0], 0, 0, 0);
        po[mi][1] = __builtin_amdgcn_mfma_f32_16x16x32_bf16(oa[mi], w1, po[mi][1], 0, 0, 0);
      }
      __builtin_amdgcn_s_setprio(0);
    }
    float* og = out + (size_t)b * 8192;
#pragma unroll
    for (int nt = 0; nt < 2; ++nt) {
      int col = (2 * w + nt) * 16 + l15;
      float bp = bproj[col];
#pragma unroll
      for (int mi = 0; mi < 4; ++mi)
#pragma unroll
        for (int reg = 0; reg < 4; ++reg)
          og[(size_t)(mi * 16 + quad * 4 + reg) * 128 + col] = po[mi][nt][reg] + bp;
    }
  }
}

extern "C" void kernel_launch(void* const* d_in, const int* in_sizes, int n_in,
                              void* d_out, int out_size, void* d_ws, size_t ws_size,
                              hipStream_t stream) {
  (void)in_sizes; (void)n_in; (void)out_size; (void)ws_size;
  const float* x     = (const float*)d_in[0];
  const float* mask  = (const float*)d_in[1];
  const float* Wqkv  = (const float*)d_in[2];
  const float* bqkv  = (const float*)d_in[3];
  const float* Wqkv2 = (const float*)d_in[4];
  const float* bqkv2 = (const float*)d_in[5];
  const float* Wp1   = (const float*)d_in[6];
  const float* bp1   = (const float*)d_in[7];
  const float* Wp2   = (const float*)d_in[8];
  const float* bp2   = (const float*)d_in[9];
  const float* lq1   = (const float*)d_in[10];
  const float* lk1   = (const float*)d_in[11];
  const float* lq2   = (const float*)d_in[12];
  const float* lk2   = (const float*)d_in[13];
  const float* subln = (const float*)d_in[14];
  const float* Wproj = (const float*)d_in[15];
  const float* bproj = (const float*)d_in[16];
  float* out = (float*)d_out;

  unsigned short* Wb = (unsigned short*)d_ws;                         // 196608 B
  float* lamBuf = (float*)((char*)d_ws + 200704);                     // 4 B (spare)
  float* pbT   = (float*)((char*)d_ws + 262144);                      // 65536 B
  float* maskT = (float*)((char*)d_ws + 327680);                      // 3145728 B

  hipLaunchKernelGGL(prep_kernel, dim3(256), dim3(256), 0, stream,
                     Wqkv, Wqkv2, Wproj, Wp1, bp1, Wp2, bp2, mask,
                     lq1, lk1, lq2, lk2, Wb, pbT, maskT, lamBuf);
  hipLaunchKernelGGL(fused_win, dim3(3072), dim3(256), 0, stream,
                     x, Wb, bqkv, bqkv2, lamBuf, subln, bproj,
                     pbT, maskT, out);
}

// Round 3
// 338.273 us; speedup vs baseline: 1.6616x; 1.6616x over previous
//
#include <hip/hip_runtime.h>
#include <math.h>

typedef __attribute__((ext_vector_type(8))) short bf16x8;
typedef __attribute__((ext_vector_type(4))) float f32x4;

#define NWMASK 192
#define SCALE_Q 0.17677669529663687f

__device__ __forceinline__ unsigned short f2bf(float f) {
  union { float f; unsigned u; } v; v.f = f;
  return (unsigned short)((v.u + 0x7fffu + ((v.u >> 16) & 1u)) >> 16);
}

__device__ __forceinline__ unsigned pkbf(float a, float b) {
#if defined(__has_builtin)
#if __has_builtin(__builtin_amdgcn_cvt_pk_bf16_f32)
  auto r = __builtin_amdgcn_cvt_pk_bf16_f32(a, b);
  union { decltype(r) v; unsigned u; } c; c.v = r; return c.u;
#else
  return (unsigned)f2bf(a) | ((unsigned)f2bf(b) << 16);
#endif
#else
  return (unsigned)f2bf(a) | ((unsigned)f2bf(b) << 16);
#endif
}

__device__ __forceinline__ void pack8s(unsigned short* dst, const float* src) {
  float4 lo = *(const float4*)(src);
  float4 hi = *(const float4*)(src + 4);
  uint4 pk;
  pk.x = pkbf(lo.x, lo.y); pk.y = pkbf(lo.z, lo.w);
  pk.z = pkbf(hi.x, hi.y); pk.w = pkbf(hi.z, hi.w);
  *(uint4*)dst = pk;
}

// ---- prep: blocks 0-47 wpack, 48-63 pbT (+lam on blk48), 64-255 maskT ----
__global__ void prep_kernel(const float* __restrict__ Wqkv, const float* __restrict__ Wqkv2,
                            const float* __restrict__ Wproj,
                            const float* __restrict__ Wp1, const float* __restrict__ bp1,
                            const float* __restrict__ Wp2, const float* __restrict__ bp2,
                            const float* __restrict__ mask,
                            const float* __restrict__ lq1, const float* __restrict__ lk1,
                            const float* __restrict__ lq2, const float* __restrict__ lk2,
                            unsigned short* __restrict__ Wb, float* __restrict__ pbT,
                            float* __restrict__ maskT, float* __restrict__ lamOut) {
  int bid = blockIdx.x;
  if (bid < 48) {
    int gid = bid * 256 + threadIdx.x;            // 12288 fragment groups
    int l15 = gid & 15, quad = (gid >> 4) & 3, ks = (gid >> 6) & 3, ft = gid >> 8;
    int row = ft * 16 + l15;
    const float* src = (row < 384) ? (Wqkv + (size_t)row * 128)
                     : (row < 640) ? (Wqkv2 + (size_t)(row - 384) * 128)
                                   : (Wproj + (size_t)(row - 640) * 128);
    pack8s(Wb + (size_t)gid * 8, src + ks * 32 + quad * 8);
  } else if (bid < 64) {
    int idx = (bid - 48) * 256 + threadIdx.x;     // (i,j), 4096 total
    int i = idx >> 6, j = idx & 63;
    float dx = (float)((i & 7) - (j & 7));
    float dy = -(float)((i >> 3) - (j >> 3));
    float r = sqrtf(dx*dx + dy*dy + 1e-9f);
    float theta = atan2f(dx, dy);
    float p0 = r * (1.0f / 9.899494936611665f);
    float p1 = (theta + 3.14159265358979323846f) * (1.0f / 6.283185307179586f);
    float a0 = 0.f, a1 = 0.f, a2 = 0.f, a3 = 0.f;
    for (int f = 0; f < 64; ++f) {
      float hpre = p0 * Wp1[2*f] + p1 * Wp1[2*f+1] + bp1[f];
      float g = 0.5f * hpre * (1.0f + erff(hpre * 0.70710678118654752f));
      a0 += Wp2[f]       * g;
      a1 += Wp2[64 + f]  * g;
      a2 += Wp2[128 + f] * g;
      a3 += Wp2[192 + f] * g;
    }
    int o = j * 64 + i;                           // transposed
    pbT[o]          = a0 + bp2[0];
    pbT[4096 + o]   = a1 + bp2[1];
    pbT[8192 + o]   = a2 + bp2[2];
    pbT[12288 + o]  = a3 + bp2[3];
    if (bid == 48 && threadIdx.x == 0) {
      float s1 = 0.f, s2 = 0.f;
      for (int k = 0; k < 16; ++k) { s1 += lq1[k]*lk1[k]; s2 += lq2[k]*lk2[k]; }
      lamOut[0] = expf(s1) - expf(s2) + 0.2f;
    }
  } else {
    // per-window LDS transpose, coalesced both sides
    __shared__ float tile[64][65];
    int wm = bid - 64;
    const float* src = mask + (size_t)wm * 4096;
#pragma unroll
    for (int u = 0; u < 4; ++u) {
      int o = u * 1024 + threadIdx.x * 4;
      float4 v = *(const float4*)(src + o);
      int r = o >> 6, c = o & 63;
      tile[r][c] = v.x; tile[r][c+1] = v.y; tile[r][c+2] = v.z; tile[r][c+3] = v.w;
    }
    __syncthreads();
    float* dst = maskT + (size_t)wm * 4096;
#pragma unroll
    for (int u = 0; u < 4; ++u) {
      int o = u * 1024 + threadIdx.x * 4;
      int c = o >> 6, r = o & 63;
      float4 v;
      v.x = tile[r][c]; v.y = tile[r+1][c]; v.z = tile[r+2][c]; v.w = tile[r+3][c];
      *(float4*)(dst + o) = v;
    }
  }
}

// ---- fully fused: one block = one window, wave w = head w ----
// LDS pool 40 KB (u16 smem[20480]), 4 blocks/CU:
//   XB  [0, 8192): x bf16 [64][128] swizzled (shared; freed at B2 -> OBUF overlay)
//   AR_w [8192 + w*3072, +2048): Q [64][32] -> P-halves [64][32]
//   BR_w [AR+2048, +1024):       K-half [32][32] -> VT-half [32][32]
// K, P, VT are halved along the token axis: produce half -> consume -> overwrite
// (intra-wave only; LDS RAW/WAR ordered by lgkmcnt, no barriers).
// softmax: plain E=exp(s), no max-sub, no normalization (row-sum cancels in RMSNorm).
__global__ __launch_bounds__(256, 4)
void fused_win(const float* __restrict__ x, const unsigned short* __restrict__ Wb,
               const float* __restrict__ bqkv, const float* __restrict__ bqkv2,
               const float* __restrict__ lamBuf,
               const float* __restrict__ subln, const float* __restrict__ bproj,
               const float* __restrict__ pbT, const float* __restrict__ maskT,
               float* __restrict__ out) {
  __shared__ unsigned short smem[20480];

  const int b = blockIdx.x;
  const int t = threadIdx.x;
  const int w = t >> 6;            // wave == head
  const int lane = t & 63;
  const int l15 = lane & 15;
  const int quad = lane >> 4;
  const int h = w;
  const f32x4 zero4 = (f32x4){0.f, 0.f, 0.f, 0.f};
  const float lam = lamBuf[0];

  // ---- stage x -> XB (read once from HBM, shared by all 4 waves) ----
  {
    const float* xg = x + (size_t)b * 8192;
#pragma unroll
    for (int u = 0; u < 4; ++u) {
      int id = u * 256 + t;
      int r = id >> 4, c16 = id & 15;
      pack8s(&smem[r * 128 + ((c16 ^ (r & 7)) * 8)], xg + r * 128 + c16 * 8);
    }
  }
  __syncthreads();                                   // B1

  unsigned short* AR = smem + 8192 + w * 3072;       // 2048 u16: Q -> P-half
  unsigned short* BR = AR + 2048;                    // 1024 u16: K-half -> VT-half

  auto ldXB = [&](int mi, int ks) -> bf16x8 {
    int row = mi * 16 + l15;
    return *(const bf16x8*)(&smem[row * 128 + (((ks * 4 + quad) ^ (l15 & 7)) * 8)]);
  };
  auto ldWbF = [&](int ft, int ks) -> bf16x8 {
    return *(const bf16x8*)(Wb + ((((size_t)ft * 4 + ks) * 4 + quad) * 16 + l15) * 8);
  };

  // 64-token x 32-dim projection, acc[4][2] (32 regs)
  auto proj2 = [&](int ft0, int ft1, f32x4 (&acc)[4][2]) {
#pragma unroll
    for (int mi = 0; mi < 4; ++mi) { acc[mi][0] = zero4; acc[mi][1] = zero4; }
#pragma unroll
    for (int ks = 0; ks < 4; ++ks) {
      bf16x8 w0 = ldWbF(ft0, ks), w1 = ldWbF(ft1, ks);
      bf16x8 xa[4];
#pragma unroll
      for (int mi = 0; mi < 4; ++mi) xa[mi] = ldXB(mi, ks);
      __builtin_amdgcn_s_setprio(1);
#pragma unroll
      for (int mi = 0; mi < 4; ++mi) {
        acc[mi][0] = __builtin_amdgcn_mfma_f32_16x16x32_bf16(xa[mi], w0, acc[mi][0], 0, 0, 0);
        acc[mi][1] = __builtin_amdgcn_mfma_f32_16x16x32_bf16(xa[mi], w1, acc[mi][1], 0, 0, 0);
      }
      __builtin_amdgcn_s_setprio(0);
    }
  };
  // Q [64][32] into AR (swizzled: elem(r,c) at r*32 + (((c>>3)^(r&3))*8) + (c&7))
  auto storeQ = [&](f32x4 (&acc)[4][2], const float* bias, float sc) {
#pragma unroll
    for (int nj = 0; nj < 2; ++nj) {
      int c32 = nj * 16 + l15;
      float bv = bias[c32];
      int g = c32 >> 3, c7 = c32 & 7;
#pragma unroll
      for (int mi = 0; mi < 4; ++mi) {
        f32x4 a = acc[mi][nj];
        unsigned p01 = pkbf((a[0] + bv) * sc, (a[1] + bv) * sc);
        unsigned p23 = pkbf((a[2] + bv) * sc, (a[3] + bv) * sc);
        int r0 = mi * 16 + quad * 4;
        AR[(r0+0) * 32 + ((g ^ ((r0+0) & 3)) * 8) + c7] = (unsigned short)p01;
        AR[(r0+1) * 32 + ((g ^ ((r0+1) & 3)) * 8) + c7] = (unsigned short)(p01 >> 16);
        AR[(r0+2) * 32 + ((g ^ ((r0+2) & 3)) * 8) + c7] = (unsigned short)p23;
        AR[(r0+3) * 32 + ((g ^ ((r0+3) & 3)) * 8) + c7] = (unsigned short)(p23 >> 16);
      }
    }
  };
  // K-half [32 tok][32 d] into BR (tokens miBase*16 .. +31), same swizzle
  auto storeKh = [&](f32x4 (&acc)[4][2], int miBase, const float* bias) {
#pragma unroll
    for (int nj = 0; nj < 2; ++nj) {
      int c32 = nj * 16 + l15;
      float bv = bias[c32];
      int g = c32 >> 3, c7 = c32 & 7;
#pragma unroll
      for (int mi = 0; mi < 2; ++mi) {
        f32x4 a = acc[miBase + mi][nj];
        unsigned p01 = pkbf(a[0] + bv, a[1] + bv);
        unsigned p23 = pkbf(a[2] + bv, a[3] + bv);
        int r0 = mi * 16 + quad * 4;
        BR[(r0+0) * 32 + ((g ^ ((r0+0) & 3)) * 8) + c7] = (unsigned short)p01;
        BR[(r0+1) * 32 + ((g ^ ((r0+1) & 3)) * 8) + c7] = (unsigned short)(p01 >> 16);
        BR[(r0+2) * 32 + ((g ^ ((r0+2) & 3)) * 8) + c7] = (unsigned short)p23;
        BR[(r0+3) * 32 + ((g ^ ((r0+3) & 3)) * 8) + c7] = (unsigned short)(p23 >> 16);
      }
    }
  };
  // S[:, half*2 + j] += Q x Khalf^T, optionally seeding C from pbT+maskT
  auto qkHalf = [&](f32x4 (&S)[4][4], int half, bool seed) {
    bf16x8 qa[4], kb[2];
#pragma unroll
    for (int mi = 0; mi < 4; ++mi) {
      int row = mi * 16 + l15;
      qa[mi] = *(const bf16x8*)(&AR[row * 32 + ((quad ^ (l15 & 3)) * 8)]);
    }
#pragma unroll
    for (int j = 0; j < 2; ++j) {
      int row = j * 16 + l15;
      kb[j] = *(const bf16x8*)(&BR[row * 32 + ((quad ^ (l15 & 3)) * 8)]);
    }
    const float* pbh = pbT + h * 4096;
    const float* mkh = maskT + (size_t)(b % NWMASK) * 4096;
    __builtin_amdgcn_s_setprio(1);
#pragma unroll
    for (int mi = 0; mi < 4; ++mi)
#pragma unroll
      for (int j = 0; j < 2; ++j) {
        int ni = half * 2 + j;
        f32x4 c;
        if (seed) {
          int off = (ni * 16 + l15) * 64 + mi * 16 + quad * 4;
          float4 p4 = *(const float4*)(pbh + off);
          float4 m4 = *(const float4*)(mkh + off);
          c[0] = p4.x + m4.x; c[1] = p4.y + m4.y;
          c[2] = p4.z + m4.z; c[3] = p4.w + m4.w;
        } else c = S[mi][ni];
        S[mi][ni] = __builtin_amdgcn_mfma_f32_16x16x32_bf16(qa[mi], kb[j], c, 0, 0, 0);
      }
    __builtin_amdgcn_s_setprio(0);
  };
  // packed E half [64 rows][32 k-tokens] -> AR (Q is dead by then)
  auto storePh = [&](unsigned (&pe)[4][4]) {
#pragma unroll
    for (int mi = 0; mi < 4; ++mi)
#pragma unroll
      for (int reg = 0; reg < 4; ++reg) {
        int row = mi * 16 + quad * 4 + reg;
        unsigned short* prow = AR + row * 32;
        int sw = row & 3;
        unsigned v = pe[mi][reg];
        prow[(((l15 >> 3) + 0) ^ sw) * 8 + (l15 & 7)] = (unsigned short)v;
        prow[(((l15 >> 3) + 2) ^ sw) * 8 + (l15 & 7)] = (unsigned short)(v >> 16);
      }
  };
  // VT-half [32 d][32 tok] -> BR (tokens miBase*16 .. +31)
  auto storeVh = [&](f32x4 (&av)[4][2], int miBase, const float* bias) {
#pragma unroll
    for (int nd = 0; nd < 2; ++nd) {
      int d = nd * 16 + l15;
      float bv = bias[d];
#pragma unroll
      for (int mi = 0; mi < 2; ++mi) {
        f32x4 a = av[miBase + mi][nd];
        int tok0 = mi * 16 + quad * 4;
        uint2 pk;
        pk.x = pkbf(a[0] + bv, a[1] + bv);
        pk.y = pkbf(a[2] + bv, a[3] + bv);
        *(uint2*)(&BR[d * 32 + ((((tok0 >> 3) ^ (d & 3))) * 8) + (tok0 & 7)]) = pk;
      }
    }
  };
  // O += Phalf x VThalf^T (both halves share the same swizzled addressing)
  auto pvHalf = [&](f32x4 (&O)[4][2]) {
    bf16x8 pa[4], vb[2];
#pragma unroll
    for (int mi = 0; mi < 4; ++mi) {
      int row = mi * 16 + l15;
      pa[mi] = *(const bf16x8*)(&AR[row * 32 + ((quad ^ (l15 & 3)) * 8)]);
    }
#pragma unroll
    for (int nd = 0; nd < 2; ++nd) {
      int d = nd * 16 + l15;
      vb[nd] = *(const bf16x8*)(&BR[d * 32 + ((quad ^ (l15 & 3)) * 8)]);
    }
    __builtin_amdgcn_s_setprio(1);
#pragma unroll
    for (int mi = 0; mi < 4; ++mi) {
      O[mi][0] = __builtin_amdgcn_mfma_f32_16x16x32_bf16(pa[mi], vb[0], O[mi][0], 0, 0, 0);
      O[mi][1] = __builtin_amdgcn_mfma_f32_16x16x32_bf16(pa[mi], vb[1], O[mi][1], 0, 0, 0);
    }
    __builtin_amdgcn_s_setprio(0);
  };

  // ===== secondary: q2' = (q2+b)*(-lam*scale); S = q2'k2 + pb + mask =====
  f32x4 S[4][4];
  {
    f32x4 acc[4][2];
    proj2(24 + 2*h, 25 + 2*h, acc);
    storeQ(acc, bqkv2 + h*32, -lam * SCALE_Q);
    proj2(32 + 2*h, 33 + 2*h, acc);
    storeKh(acc, 0, bqkv2 + 128 + h*32);
    qkHalf(S, 0, true);
    storeKh(acc, 2, bqkv2 + 128 + h*32);
    qkHalf(S, 1, true);
  }
  // ===== primary: q,k -> S += qk =====
  {
    f32x4 acc[4][2];
    proj2(2*h, 1 + 2*h, acc);
    storeQ(acc, bqkv + h*32, SCALE_Q);
    proj2(8 + 2*h, 9 + 2*h, acc);
    storeKh(acc, 0, bqkv + 128 + h*32);
    qkHalf(S, 0, false);
    storeKh(acc, 2, bqkv + 128 + h*32);
    qkHalf(S, 1, false);
  }

  // ===== E = exp(S) packed bf16; S dies here =====
  unsigned pe01[4][4], pe23[4][4];
#pragma unroll
  for (int mi = 0; mi < 4; ++mi)
#pragma unroll
    for (int reg = 0; reg < 4; ++reg) {
      pe01[mi][reg] = pkbf(__expf(S[mi][0][reg]), __expf(S[mi][1][reg]));
      pe23[mi][reg] = pkbf(__expf(S[mi][2][reg]), __expf(S[mi][3][reg]));
    }
  storePh(pe01);                          // P k-tokens 0..31 -> AR

  // ===== v projection (LAST XB reads) =====
  f32x4 av[4][2];
  proj2(16 + 2*h, 17 + 2*h, av);

  __syncthreads();                                   // B2: XB free from here

  // ===== PV in two token-halves -> O; RMSNorm folds softmax sum away =====
  float ov0[4][4], ov1[4][4];
  {
    const float* vbias = bqkv + 256 + h * 32;
    f32x4 O[4][2];
#pragma unroll
    for (int mi = 0; mi < 4; ++mi) { O[mi][0] = zero4; O[mi][1] = zero4; }
    storeVh(av, 0, vbias);                // VT tokens 0..31
    pvHalf(O);
    storePh(pe23);                        // P k-tokens 32..63
    storeVh(av, 2, vbias);                // VT tokens 32..63
    pvHalf(O);

    float sw0 = subln[l15] * 0.8f;
    float sw1 = subln[16 + l15] * 0.8f;
#pragma unroll
    for (int mi = 0; mi < 4; ++mi)
#pragma unroll
      for (int reg = 0; reg < 4; ++reg) {
        float a0 = O[mi][0][reg], a1 = O[mi][1][reg];
        float ss = a0 * a0 + a1 * a1;
        ss += __shfl_xor(ss, 1);
        ss += __shfl_xor(ss, 2);
        ss += __shfl_xor(ss, 4);
        ss += __shfl_xor(ss, 8);
        float rs = 1.0f / sqrtf(ss * (1.0f / 32.0f));   // eps*sum^2 negligible
        ov0[mi][reg] = a0 * rs * sw0;
        ov1[mi][reg] = a1 * rs * sw1;
      }
  }

  // ===== O -> OBUF [64][128] bf16 at smem[0,8192) (overlays XB) =====
  {
    int c0 = h * 32 + l15, c1 = h * 32 + 16 + l15;
#pragma unroll
    for (int mi = 0; mi < 4; ++mi)
#pragma unroll
      for (int reg = 0; reg < 4; ++reg) {
        int row = mi * 16 + quad * 4 + reg;
        unsigned short* orow = smem + row * 128;
        unsigned p = pkbf(ov0[mi][reg], ov1[mi][reg]);
        orow[(((c0 >> 3) ^ (row & 7)) * 8) + (c0 & 7)] = (unsigned short)p;
        orow[(((c1 >> 3) ^ (row & 7)) * 8) + (c1 & 7)] = (unsigned short)(p >> 16);
      }
  }
  __syncthreads();                                   // B3

  // ===== out-projection =====
  {
    f32x4 po[4][2];
#pragma unroll
    for (int mi = 0; mi < 4; ++mi) { po[mi][0] = zero4; po[mi][1] = zero4; }
#pragma unroll
    for (int ks = 0; ks < 4; ++ks) {
      bf16x8 oa[4];
#pragma unroll
      for (int mi = 0; mi < 4; ++mi) {
        int row = mi * 16 + l15;
        oa[mi] = *(const bf16x8*)(&smem[row * 128 + (((ks * 4 + quad) ^ (l15 & 7)) * 8)]);
      }
      bf16x8 w0 = ldWbF(40 + 2*w, ks), w1 = ldWbF(41 + 2*w, ks);
      __builtin_amdgcn_s_setprio(1);
#pragma unroll
      for (int mi = 0; mi < 4; ++mi) {
        po[mi][0] = __builtin_amdgcn_mfma_f32_16x16x32_bf16(oa[mi], w0, po[mi][0], 0, 0, 0);
        po[mi][1] = __builtin_amdgcn_mfma_f32_16x16x32_bf16(oa[mi], w1, po[mi][1], 0, 0, 0);
      }
      __builtin_amdgcn_s_setprio(0);
    }
    float* og = out + (size_t)b * 8192;
#pragma unroll
    for (int nt = 0; nt < 2; ++nt) {
      int col = (2 * w + nt) * 16 + l15;
      float bp = bproj[col];
#pragma unroll
      for (int mi = 0; mi < 4; ++mi)
#pragma unroll
        for (int reg = 0; reg < 4; ++reg)
          og[(size_t)(mi * 16 + quad * 4 + reg) * 128 + col] = po[mi][nt][reg] + bp;
    }
  }
}

extern "C" void kernel_launch(void* const* d_in, const int* in_sizes, int n_in,
                              void* d_out, int out_size, void* d_ws, size_t ws_size,
                              hipStream_t stream) {
  (void)in_sizes; (void)n_in; (void)out_size; (void)ws_size;
  const float* x     = (const float*)d_in[0];
  const float* mask  = (const float*)d_in[1];
  const float* Wqkv  = (const float*)d_in[2];
  const float* bqkv  = (const float*)d_in[3];
  const float* Wqkv2 = (const float*)d_in[4];
  const float* bqkv2 = (const float*)d_in[5];
  const float* Wp1   = (const float*)d_in[6];
  const float* bp1   = (const float*)d_in[7];
  const float* Wp2   = (const float*)d_in[8];
  const float* bp2   = (const float*)d_in[9];
  const float* lq1   = (const float*)d_in[10];
  const float* lk1   = (const float*)d_in[11];
  const float* lq2   = (const float*)d_in[12];
  const float* lk2   = (const float*)d_in[13];
  const float* subln = (const float*)d_in[14];
  const float* Wproj = (const float*)d_in[15];
  const float* bproj = (const float*)d_in[16];
  float* out = (float*)d_out;

  unsigned short* Wb = (unsigned short*)d_ws;                         // 196608 B
  float* lamBuf = (float*)((char*)d_ws + 200704);                     // 4 B (spare)
  float* pbT   = (float*)((char*)d_ws + 262144);                      // 65536 B
  float* maskT = (float*)((char*)d_ws + 327680);                      // 3145728 B

  hipLaunchKernelGGL(prep_kernel, dim3(256), dim3(256), 0, stream,
                     Wqkv, Wqkv2, Wproj, Wp1, bp1, Wp2, bp2, mask,
                     lq1, lk1, lq2, lk2, Wb, pbT, maskT, lamBuf);
  hipLaunchKernelGGL(fused_win, dim3(3072), dim3(256), 0, stream,
                     x, Wb, bqkv, bqkv2, lamBuf, subln, bproj,
                     pbT, maskT, out);
}

// Round 4
// 324.465 us; speedup vs baseline: 1.7323x; 1.0426x over previous
//
#include <hip/hip_runtime.h>
#include <math.h>

typedef __attribute__((ext_vector_type(8))) short bf16x8;
typedef __attribute__((ext_vector_type(4))) float f32x4;

#define NWMASK 192
#define SCALE_Q 0.17677669529663687f

__device__ __forceinline__ unsigned short f2bf(float f) {
  union { float f; unsigned u; } v; v.f = f;
  return (unsigned short)((v.u + 0x7fffu + ((v.u >> 16) & 1u)) >> 16);
}

__device__ __forceinline__ unsigned pkbf(float a, float b) {
#if defined(__has_builtin)
#if __has_builtin(__builtin_amdgcn_cvt_pk_bf16_f32)
  auto r = __builtin_amdgcn_cvt_pk_bf16_f32(a, b);
  union { decltype(r) v; unsigned u; } c; c.v = r; return c.u;
#else
  return (unsigned)f2bf(a) | ((unsigned)f2bf(b) << 16);
#endif
#else
  return (unsigned)f2bf(a) | ((unsigned)f2bf(b) << 16);
#endif
}

__device__ __forceinline__ void pack8s(unsigned short* dst, const float* src) {
  float4 lo = *(const float4*)(src);
  float4 hi = *(const float4*)(src + 4);
  uint4 pk;
  pk.x = pkbf(lo.x, lo.y); pk.y = pkbf(lo.z, lo.w);
  pk.z = pkbf(hi.x, hi.y); pk.w = pkbf(hi.z, hi.w);
  *(uint4*)dst = pk;
}

// ---- prep: blocks 0-47 wpack, 48-63 pbT (+lam on blk48), 64-255 maskT ----
__global__ void prep_kernel(const float* __restrict__ Wqkv, const float* __restrict__ Wqkv2,
                            const float* __restrict__ Wproj,
                            const float* __restrict__ Wp1, const float* __restrict__ bp1,
                            const float* __restrict__ Wp2, const float* __restrict__ bp2,
                            const float* __restrict__ mask,
                            const float* __restrict__ lq1, const float* __restrict__ lk1,
                            const float* __restrict__ lq2, const float* __restrict__ lk2,
                            unsigned short* __restrict__ Wb, float* __restrict__ pbT,
                            float* __restrict__ maskT, float* __restrict__ lamOut) {
  int bid = blockIdx.x;
  if (bid < 48) {
    int gid = bid * 256 + threadIdx.x;            // 12288 fragment groups
    int l15 = gid & 15, quad = (gid >> 4) & 3, ks = (gid >> 6) & 3, ft = gid >> 8;
    int row = ft * 16 + l15;
    const float* src = (row < 384) ? (Wqkv + (size_t)row * 128)
                     : (row < 640) ? (Wqkv2 + (size_t)(row - 384) * 128)
                                   : (Wproj + (size_t)(row - 640) * 128);
    pack8s(Wb + (size_t)gid * 8, src + ks * 32 + quad * 8);
  } else if (bid < 64) {
    int idx = (bid - 48) * 256 + threadIdx.x;     // (i,j), 4096 total
    int i = idx >> 6, j = idx & 63;
    float dx = (float)((i & 7) - (j & 7));
    float dy = -(float)((i >> 3) - (j >> 3));
    float r = sqrtf(dx*dx + dy*dy + 1e-9f);
    float theta = atan2f(dx, dy);
    float p0 = r * (1.0f / 9.899494936611665f);
    float p1 = (theta + 3.14159265358979323846f) * (1.0f / 6.283185307179586f);
    float a0 = 0.f, a1 = 0.f, a2 = 0.f, a3 = 0.f;
    for (int f = 0; f < 64; ++f) {
      float hpre = p0 * Wp1[2*f] + p1 * Wp1[2*f+1] + bp1[f];
      float g = 0.5f * hpre * (1.0f + erff(hpre * 0.70710678118654752f));
      a0 += Wp2[f]       * g;
      a1 += Wp2[64 + f]  * g;
      a2 += Wp2[128 + f] * g;
      a3 += Wp2[192 + f] * g;
    }
    int o = j * 64 + i;                           // transposed
    pbT[o]          = a0 + bp2[0];
    pbT[4096 + o]   = a1 + bp2[1];
    pbT[8192 + o]   = a2 + bp2[2];
    pbT[12288 + o]  = a3 + bp2[3];
    if (bid == 48 && threadIdx.x == 0) {
      float s1 = 0.f, s2 = 0.f;
      for (int k = 0; k < 16; ++k) { s1 += lq1[k]*lk1[k]; s2 += lq2[k]*lk2[k]; }
      lamOut[0] = expf(s1) - expf(s2) + 0.2f;
    }
  } else {
    // per-window LDS transpose, coalesced both sides
    __shared__ float tile[64][65];
    int wm = bid - 64;
    const float* src = mask + (size_t)wm * 4096;
#pragma unroll
    for (int u = 0; u < 4; ++u) {
      int o = u * 1024 + threadIdx.x * 4;
      float4 v = *(const float4*)(src + o);
      int r = o >> 6, c = o & 63;
      tile[r][c] = v.x; tile[r][c+1] = v.y; tile[r][c+2] = v.z; tile[r][c+3] = v.w;
    }
    __syncthreads();
    float* dst = maskT + (size_t)wm * 4096;
#pragma unroll
    for (int u = 0; u < 4; ++u) {
      int o = u * 1024 + threadIdx.x * 4;
      int c = o >> 6, r = o & 63;
      float4 v;
      v.x = tile[r][c]; v.y = tile[r+1][c]; v.z = tile[r+2][c]; v.w = tile[r+3][c];
      *(float4*)(dst + o) = v;
    }
  }
}

// ---- fused: one block = one window, 8 waves = 4 heads x 2 q-token-halves ----
// Wave w: head h=w>>1, token-half m=w&1 (q-rows Rb=m*32 .. +31).
// LDS 48 KB (u16 smem[24576]), 3 blocks/CU:
//   XB [0,8192): x bf16 [64][128] swizzled; after B6 -> VT_h [32 d][64 tok] at h*2048
//   head region h: [8192+h*4096, +4096): QBUF [64][32] (2048) + KBUF [64][32] (2048)
//                  after B5 -> P [64 q][64 k] bf16 (4096)
//   after B8: OBUF [64][128] bf16 at [8192,16384) (overlays P of heads 0,1)
// Each wave projects its OWN 32 tokens for q/k/v (K,V halves are cross-read by
// the head pair -> block barriers B2/B4/B7). S[2][4]=32 regs; peak live ~78
// -> __launch_bounds__(512,6): 85-reg cap, 3 blocks/CU, no spills.
// softmax: plain E=exp(s), unnormalized (row-sum cancels in RMSNorm).
__global__ __launch_bounds__(512, 6)
void fused_win(const float* __restrict__ x, const unsigned short* __restrict__ Wb,
               const float* __restrict__ bqkv, const float* __restrict__ bqkv2,
               const float* __restrict__ lamBuf,
               const float* __restrict__ subln, const float* __restrict__ bproj,
               const float* __restrict__ pbT, const float* __restrict__ maskT,
               float* __restrict__ out) {
  __shared__ unsigned short smem[24576];

  const int b = blockIdx.x;
  const int t = threadIdx.x;
  const int w = t >> 6;
  const int h = w >> 1;            // head
  const int m = w & 1;             // q-token half
  const int lane = t & 63;
  const int l15 = lane & 15;
  const int quad = lane >> 4;
  const int Rb = m * 32;           // own q/k/v token base
  const f32x4 zero4 = (f32x4){0.f, 0.f, 0.f, 0.f};
  const float lam = lamBuf[0];

  // ---- stage x -> XB ----
  {
    const float* xg = x + (size_t)b * 8192;
#pragma unroll
    for (int u = 0; u < 2; ++u) {
      int id = u * 512 + t;
      int r = id >> 4, c16 = id & 15;
      pack8s(&smem[r * 128 + ((c16 ^ (r & 7)) * 8)], xg + r * 128 + c16 * 8);
    }
  }
  __syncthreads();                                   // B1

  unsigned short* QB = smem + 8192 + h * 4096;       // [64][32] swizzled
  unsigned short* KB = QB + 2048;                    // [64][32] swizzled
  unsigned short* PB = QB;                           // P [64][64] overlays QB+KB
  unsigned short* VT = smem + h * 2048;              // [32 d][64 tok] in XB (after B6)

  auto ldXB = [&](int mi, int ks) -> bf16x8 {
    int row = Rb + mi * 16 + l15;
    return *(const bf16x8*)(&smem[row * 128 + (((ks * 4 + quad) ^ (l15 & 7)) * 8)]);
  };
  auto ldWbF = [&](int ft, int ks) -> bf16x8 {
    return *(const bf16x8*)(Wb + ((((size_t)ft * 4 + ks) * 4 + quad) * 16 + l15) * 8);
  };

  // own 32 tokens x 32 dims projection, acc[2][2] (16 regs)
  auto proj2h = [&](int ft0, int ft1, f32x4 (&acc)[2][2]) {
#pragma unroll
    for (int mi = 0; mi < 2; ++mi) { acc[mi][0] = zero4; acc[mi][1] = zero4; }
#pragma unroll
    for (int ks = 0; ks < 4; ++ks) {
      bf16x8 w0 = ldWbF(ft0, ks), w1 = ldWbF(ft1, ks);
      bf16x8 xa[2];
#pragma unroll
      for (int mi = 0; mi < 2; ++mi) xa[mi] = ldXB(mi, ks);
      __builtin_amdgcn_s_setprio(1);
#pragma unroll
      for (int mi = 0; mi < 2; ++mi) {
        acc[mi][0] = __builtin_amdgcn_mfma_f32_16x16x32_bf16(xa[mi], w0, acc[mi][0], 0, 0, 0);
        acc[mi][1] = __builtin_amdgcn_mfma_f32_16x16x32_bf16(xa[mi], w1, acc[mi][1], 0, 0, 0);
      }
      __builtin_amdgcn_s_setprio(0);
    }
  };
  // own 32 rows into a [64][32] buffer (rows Rb..Rb+31), swizzle ^(row&3)
  auto storeM32 = [&](unsigned short* buf, f32x4 (&acc)[2][2], const float* bias, float sc) {
#pragma unroll
    for (int nj = 0; nj < 2; ++nj) {
      int c32 = nj * 16 + l15;
      float bv = bias[c32];
      int g = c32 >> 3, c7 = c32 & 7;
#pragma unroll
      for (int mi = 0; mi < 2; ++mi) {
        f32x4 a = acc[mi][nj];
        unsigned p01 = pkbf((a[0] + bv) * sc, (a[1] + bv) * sc);
        unsigned p23 = pkbf((a[2] + bv) * sc, (a[3] + bv) * sc);
        int r0 = Rb + mi * 16 + quad * 4;
        buf[(r0+0) * 32 + ((g ^ ((r0+0) & 3)) * 8) + c7] = (unsigned short)p01;
        buf[(r0+1) * 32 + ((g ^ ((r0+1) & 3)) * 8) + c7] = (unsigned short)(p01 >> 16);
        buf[(r0+2) * 32 + ((g ^ ((r0+2) & 3)) * 8) + c7] = (unsigned short)p23;
        buf[(r0+3) * 32 + ((g ^ ((r0+3) & 3)) * 8) + c7] = (unsigned short)(p23 >> 16);
      }
    }
  };
  // S[2][4] (+)= Q(own rows) x K(all 64)^T, optionally seeding from pbT+maskT
  auto qkAll = [&](f32x4 (&S)[2][4], bool seed) {
    bf16x8 qa[2], kb[4];
#pragma unroll
    for (int mi = 0; mi < 2; ++mi) {
      int row = Rb + mi * 16 + l15;
      qa[mi] = *(const bf16x8*)(&QB[row * 32 + ((quad ^ (l15 & 3)) * 8)]);
    }
#pragma unroll
    for (int ni = 0; ni < 4; ++ni) {
      int row = ni * 16 + l15;
      kb[ni] = *(const bf16x8*)(&KB[row * 32 + ((quad ^ (l15 & 3)) * 8)]);
    }
    const float* pbh = pbT + h * 4096;
    const float* mkh = maskT + (size_t)(b % NWMASK) * 4096;
    __builtin_amdgcn_s_setprio(1);
#pragma unroll
    for (int mi = 0; mi < 2; ++mi)
#pragma unroll
      for (int ni = 0; ni < 4; ++ni) {
        f32x4 c;
        if (seed) {
          int off = (ni * 16 + l15) * 64 + Rb + mi * 16 + quad * 4;
          float4 p4 = *(const float4*)(pbh + off);
          float4 m4 = *(const float4*)(mkh + off);
          c[0] = p4.x + m4.x; c[1] = p4.y + m4.y;
          c[2] = p4.z + m4.z; c[3] = p4.w + m4.w;
        } else c = S[mi][ni];
        S[mi][ni] = __builtin_amdgcn_mfma_f32_16x16x32_bf16(qa[mi], kb[ni], c, 0, 0, 0);
      }
    __builtin_amdgcn_s_setprio(0);
  };

  // ===== secondary: q2' = (q2+b)*(-lam*scale), k2 =====
  f32x4 S[2][4];
  {
    f32x4 acc[2][2];
    proj2h(24 + 2*h, 25 + 2*h, acc);
    storeM32(QB, acc, bqkv2 + h*32, -lam * SCALE_Q);
    proj2h(32 + 2*h, 33 + 2*h, acc);
    storeM32(KB, acc, bqkv2 + 128 + h*32, 1.0f);
  }
  __syncthreads();                                   // B2: Q2,K2 complete
  qkAll(S, true);
  __syncthreads();                                   // B3: qk2 reads done
  // ===== primary: q,k =====
  {
    f32x4 acc[2][2];
    proj2h(2*h, 1 + 2*h, acc);
    storeM32(QB, acc, bqkv + h*32, SCALE_Q);
    proj2h(8 + 2*h, 9 + 2*h, acc);
    storeM32(KB, acc, bqkv + 128 + h*32, 1.0f);
  }
  __syncthreads();                                   // B4: Q,K complete
  qkAll(S, false);

  // ===== E = exp(S) packed bf16 (registers only) =====
  unsigned pe01[2][4], pe23[2][4];
#pragma unroll
  for (int mi = 0; mi < 2; ++mi)
#pragma unroll
    for (int reg = 0; reg < 4; ++reg) {
      pe01[mi][reg] = pkbf(__expf(S[mi][0][reg]), __expf(S[mi][1][reg]));
      pe23[mi][reg] = pkbf(__expf(S[mi][2][reg]), __expf(S[mi][3][reg]));
    }
  __syncthreads();                                   // B5: qk1 reads done -> P may overwrite
  // ===== P (own 32 rows) -> PB [64 q][64 k], swizzle ^(row&7) =====
#pragma unroll
  for (int mi = 0; mi < 2; ++mi)
#pragma unroll
    for (int reg = 0; reg < 4; ++reg) {
      int row = Rb + mi * 16 + quad * 4 + reg;
      unsigned short* prow = PB + row * 64;
      int sw = row & 7;
      unsigned v01 = pe01[mi][reg], v23 = pe23[mi][reg];
      prow[(((l15 >> 3) + 0) ^ sw) * 8 + (l15 & 7)] = (unsigned short)v01;
      prow[(((l15 >> 3) + 2) ^ sw) * 8 + (l15 & 7)] = (unsigned short)(v01 >> 16);
      prow[(((l15 >> 3) + 4) ^ sw) * 8 + (l15 & 7)] = (unsigned short)v23;
      prow[(((l15 >> 3) + 6) ^ sw) * 8 + (l15 & 7)] = (unsigned short)(v23 >> 16);
    }

  // ===== v projection (LAST XB reads) =====
  f32x4 av[2][2];
  proj2h(16 + 2*h, 17 + 2*h, av);
  __syncthreads();                                   // B6: all XB reads done
  // ===== VT (own 32 tokens) -> [32 d][64 tok] in XB =====
  {
    const float* vbias = bqkv + 256 + h * 32;
#pragma unroll
    for (int nd = 0; nd < 2; ++nd) {
      int d = nd * 16 + l15;
      float bv = vbias[d];
#pragma unroll
      for (int mi = 0; mi < 2; ++mi) {
        int tok = Rb + mi * 16 + quad * 4;
        uint2 pk;
        pk.x = pkbf(av[mi][nd][0] + bv, av[mi][nd][1] + bv);
        pk.y = pkbf(av[mi][nd][2] + bv, av[mi][nd][3] + bv);
        *(uint2*)(&VT[d * 64 + (((tok >> 3) ^ (d & 7)) * 8) + (tok & 7)]) = pk;
      }
    }
  }
  __syncthreads();                                   // B7: VT complete

  // ===== PV: O[2][2] = P(own rows) x VT^T; RMSNorm folds softmax sum =====
  float ov0[2][4], ov1[2][4];
  {
    f32x4 O[2][2];
#pragma unroll
    for (int mi = 0; mi < 2; ++mi) { O[mi][0] = zero4; O[mi][1] = zero4; }
#pragma unroll
    for (int kc = 0; kc < 2; ++kc) {
      bf16x8 pa[2], vb[2];
#pragma unroll
      for (int mi = 0; mi < 2; ++mi) {
        int row = Rb + mi * 16 + l15;
        pa[mi] = *(const bf16x8*)(&PB[row * 64 + (((kc * 4 + quad) ^ (row & 7)) * 8)]);
      }
#pragma unroll
      for (int nd = 0; nd < 2; ++nd) {
        int d = nd * 16 + l15;
        vb[nd] = *(const bf16x8*)(&VT[d * 64 + (((kc * 4 + quad) ^ (d & 7)) * 8)]);
      }
      __builtin_amdgcn_s_setprio(1);
#pragma unroll
      for (int mi = 0; mi < 2; ++mi) {
        O[mi][0] = __builtin_amdgcn_mfma_f32_16x16x32_bf16(pa[mi], vb[0], O[mi][0], 0, 0, 0);
        O[mi][1] = __builtin_amdgcn_mfma_f32_16x16x32_bf16(pa[mi], vb[1], O[mi][1], 0, 0, 0);
      }
      __builtin_amdgcn_s_setprio(0);
    }
    float sw0 = subln[l15] * 0.8f;
    float sw1 = subln[16 + l15] * 0.8f;
#pragma unroll
    for (int mi = 0; mi < 2; ++mi)
#pragma unroll
      for (int reg = 0; reg < 4; ++reg) {
        float a0 = O[mi][0][reg], a1 = O[mi][1][reg];
        float ss = a0 * a0 + a1 * a1;
        ss += __shfl_xor(ss, 1);
        ss += __shfl_xor(ss, 2);
        ss += __shfl_xor(ss, 4);
        ss += __shfl_xor(ss, 8);
        float rs = 1.0f / sqrtf(ss * (1.0f / 32.0f));   // eps*sum^2 negligible
        ov0[mi][reg] = a0 * rs * sw0;
        ov1[mi][reg] = a1 * rs * sw1;
      }
  }
  __syncthreads();                                   // B8: P(h0,h1) reads done

  // ===== O -> OBUF [64][128] bf16 at smem[8192..16384) =====
  {
    unsigned short* OB = smem + 8192;
    int c0 = h * 32 + l15, c1 = h * 32 + 16 + l15;
#pragma unroll
    for (int mi = 0; mi < 2; ++mi)
#pragma unroll
      for (int reg = 0; reg < 4; ++reg) {
        int row = Rb + mi * 16 + quad * 4 + reg;
        unsigned short* orow = OB + row * 128;
        unsigned p = pkbf(ov0[mi][reg], ov1[mi][reg]);
        orow[(((c0 >> 3) ^ (row & 7)) * 8) + (c0 & 7)] = (unsigned short)p;
        orow[(((c1 >> 3) ^ (row & 7)) * 8) + (c1 & 7)] = (unsigned short)(p >> 16);
      }
  }
  __syncthreads();                                   // B9: OBUF complete

  // ===== out-projection: own 32 rows x cols h*32..+31 =====
  {
    unsigned short* OB = smem + 8192;
    f32x4 po[2][2];
#pragma unroll
    for (int mi = 0; mi < 2; ++mi) { po[mi][0] = zero4; po[mi][1] = zero4; }
#pragma unroll
    for (int ks = 0; ks < 4; ++ks) {
      bf16x8 oa[2];
#pragma unroll
      for (int mi = 0; mi < 2; ++mi) {
        int row = Rb + mi * 16 + l15;
        oa[mi] = *(const bf16x8*)(&OB[row * 128 + (((ks * 4 + quad) ^ (l15 & 7)) * 8)]);
      }
      bf16x8 w0 = ldWbF(40 + 2*h, ks), w1 = ldWbF(41 + 2*h, ks);
      __builtin_amdgcn_s_setprio(1);
#pragma unroll
      for (int mi = 0; mi < 2; ++mi) {
        po[mi][0] = __builtin_amdgcn_mfma_f32_16x16x32_bf16(oa[mi], w0, po[mi][0], 0, 0, 0);
        po[mi][1] = __builtin_amdgcn_mfma_f32_16x16x32_bf16(oa[mi], w1, po[mi][1], 0, 0, 0);
      }
      __builtin_amdgcn_s_setprio(0);
    }
    float* og = out + (size_t)b * 8192;
#pragma unroll
    for (int nt = 0; nt < 2; ++nt) {
      int col = h * 32 + nt * 16 + l15;
      float bp = bproj[col];
#pragma unroll
      for (int mi = 0; mi < 2; ++mi)
#pragma unroll
        for (int reg = 0; reg < 4; ++reg)
          og[(size_t)(Rb + mi * 16 + quad * 4 + reg) * 128 + col] = po[mi][nt][reg] + bp;
    }
  }
}

extern "C" void kernel_launch(void* const* d_in, const int* in_sizes, int n_in,
                              void* d_out, int out_size, void* d_ws, size_t ws_size,
                              hipStream_t stream) {
  (void)in_sizes; (void)n_in; (void)out_size; (void)ws_size;
  const float* x     = (const float*)d_in[0];
  const float* mask  = (const float*)d_in[1];
  const float* Wqkv  = (const float*)d_in[2];
  const float* bqkv  = (const float*)d_in[3];
  const float* Wqkv2 = (const float*)d_in[4];
  const float* bqkv2 = (const float*)d_in[5];
  const float* Wp1   = (const float*)d_in[6];
  const float* bp1   = (const float*)d_in[7];
  const float* Wp2   = (const float*)d_in[8];
  const float* bp2   = (const float*)d_in[9];
  const float* lq1   = (const float*)d_in[10];
  const float* lk1   = (const float*)d_in[11];
  const float* lq2   = (const float*)d_in[12];
  const float* lk2   = (const float*)d_in[13];
  const float* subln = (const float*)d_in[14];
  const float* Wproj = (const float*)d_in[15];
  const float* bproj = (const float*)d_in[16];
  float* out = (float*)d_out;

  unsigned short* Wb = (unsigned short*)d_ws;                         // 196608 B
  float* lamBuf = (float*)((char*)d_ws + 200704);                     // 4 B (spare)
  float* pbT   = (float*)((char*)d_ws + 262144);                      // 65536 B
  float* maskT = (float*)((char*)d_ws + 327680);                      // 3145728 B

  hipLaunchKernelGGL(prep_kernel, dim3(256), dim3(256), 0, stream,
                     Wqkv, Wqkv2, Wproj, Wp1, bp1, Wp2, bp2, mask,
                     lq1, lk1, lq2, lk2, Wb, pbT, maskT, lamBuf);
  hipLaunchKernelGGL(fused_win, dim3(3072), dim3(512), 0, stream,
                     x, Wb, bqkv, bqkv2, lamBuf, subln, bproj,
                     pbT, maskT, out);
}